// Round 4
// baseline (401.273 us; speedup 1.0000x reference)
//
#include <hip/hip_runtime.h>
#include <stdint.h>

#define D 128
#define NCLS 64
#define BSH 7       // 128 nodes per bucket
#define NBMAX 1024  // max buckets (N <= 131072)
#define CCHUNK 4096 // edges per k_bscatter block

typedef __bf16 bf16x8 __attribute__((ext_vector_type(8)));
typedef float f32x4 __attribute__((ext_vector_type(4)));
typedef float f32x2 __attribute__((ext_vector_type(2)));

union B8 { uint4 u; bf16x8 v; };

// pack 8 f32 -> 8 bf16 fragment
__device__ __forceinline__ B8 pack8(const float4& a, const float4& b) {
  union { __bf16 h[8]; uint4 u; } p;
  p.h[0] = (__bf16)a.x; p.h[1] = (__bf16)a.y; p.h[2] = (__bf16)a.z; p.h[3] = (__bf16)a.w;
  p.h[4] = (__bf16)b.x; p.h[5] = (__bf16)b.y; p.h[6] = (__bf16)b.z; p.h[7] = (__bf16)b.w;
  B8 r; r.u = p.u; return r;
}

// ---- bucketed CSR build --------------------------------------------------

__global__ __launch_bounds__(256) void k_bhist(const int* __restrict__ dst,
                                               int* __restrict__ bcnt, int E, int NB) {
  __shared__ int h[NBMAX];
  for (int i = threadIdx.x; i < NB; i += 256) h[i] = 0;
  __syncthreads();
  for (int e = blockIdx.x * 256 + threadIdx.x; e < E; e += gridDim.x * 256)
    atomicAdd(&h[dst[e] >> BSH], 1);
  __syncthreads();
  for (int i = threadIdx.x; i < NB; i += 256) {
    int c = h[i];
    if (c) atomicAdd(&bcnt[i], c);
  }
}

__global__ __launch_bounds__(1024) void k_bscan(const int* __restrict__ bcnt,
                                                int* __restrict__ bbase,
                                                int* __restrict__ bcur, int NB, int E) {
  __shared__ int sm[NBMAX];
  const int tid = threadIdx.x;
  int v = (tid < NB) ? bcnt[tid] : 0;
  sm[tid] = v;
  __syncthreads();
  for (int off = 1; off < NBMAX; off <<= 1) {
    int t = (tid >= off) ? sm[tid - off] : 0;
    __syncthreads();
    sm[tid] += t;
    __syncthreads();
  }
  if (tid < NB) {
    bbase[tid] = sm[tid] - v;
    bcur[tid] = sm[tid] - v;
  }
  if (tid == 0) bbase[NB] = E;
}

__global__ __launch_bounds__(256) void k_bscatter(const int* __restrict__ src,
                                                  const int* __restrict__ dst,
                                                  int* __restrict__ bcur,
                                                  int* __restrict__ ebuck, int E, int NB) {
  __shared__ int h[NBMAX];
  __shared__ int base[NBMAX];
  const int beg = blockIdx.x * CCHUNK;
  const int end = min(beg + CCHUNK, E);
  for (int i = threadIdx.x; i < NB; i += 256) h[i] = 0;
  __syncthreads();
  for (int e = beg + threadIdx.x; e < end; e += 256)
    atomicAdd(&h[dst[e] >> BSH], 1);
  __syncthreads();
  for (int i = threadIdx.x; i < NB; i += 256) {
    int c = h[i];
    base[i] = c ? atomicAdd(&bcur[i], c) : 0;
    h[i] = 0;  // becomes local rank cursor
  }
  __syncthreads();
  for (int e = beg + threadIdx.x; e < end; e += 256) {
    const int d = dst[e];
    const int b = d >> BSH;
    const int r = atomicAdd(&h[b], 1);
    ebuck[base[b] + r] = (src[e] << BSH) | (d & 127);
  }
}

__global__ __launch_bounds__(256) void k_bbuild(const int* __restrict__ ebuck,
                                                const int* __restrict__ bbase,
                                                int* __restrict__ row_ptr,
                                                int* __restrict__ esrc,
                                                float* __restrict__ inv, int N, int E) {
  __shared__ int cnt[128], s[128], cur[128];
  const int b = blockIdx.x;
  const int n0 = b << BSH;
  const int nn = min(128, N - n0);
  const int beg = bbase[b], end = bbase[b + 1];
  const int tid = threadIdx.x;
  if (tid < 128) cnt[tid] = 0;
  __syncthreads();
  for (int e = beg + tid; e < end; e += 256)
    atomicAdd(&cnt[ebuck[e] & 127], 1);
  __syncthreads();
  if (tid < 128) s[tid] = cnt[tid];
  __syncthreads();
  for (int off = 1; off < 128; off <<= 1) {
    int t = (tid < 128 && tid >= off) ? s[tid - off] : 0;
    __syncthreads();
    if (tid < 128) s[tid] += t;
    __syncthreads();
  }
  if (tid < 128) {
    const int ex = s[tid] - cnt[tid];
    cur[tid] = ex;
    if (tid < nn) {
      row_ptr[n0 + tid] = beg + ex;
      inv[n0 + tid] = 1.0f / fmaxf((float)cnt[tid], 1.0f);
    }
  }
  if (b == 0 && tid == 0) row_ptr[N] = E;
  __syncthreads();
  for (int e = beg + tid; e < end; e += 256) {
    const int p = ebuck[e];
    const int r = atomicAdd(&cur[p & 127], 1);
    esrc[beg + r] = p >> BSH;
  }
}

// ---- z1 = feat(f32) @ W1^T, bf16 out (no bias/relu) ----------------------

__global__ __launch_bounds__(256) void k_gemmz1(const float* __restrict__ A,
                                                const float* __restrict__ W,
                                                ushort* __restrict__ Z, int N) {
  const int wave = threadIdx.x >> 6;
  const int lane = threadIdx.x & 63;
  const int l15 = lane & 15;
  const int quad = lane >> 4;

  B8 bfrag[2][4];
#pragma unroll
  for (int t = 0; t < 2; ++t) {
    const int n = wave * 32 + t * 16 + l15;
    const float* wp = W + (size_t)n * D + quad * 8;
#pragma unroll
    for (int ks = 0; ks < 4; ++ks)
      bfrag[t][ks] = pack8(*reinterpret_cast<const float4*>(wp + ks * 32),
                           *reinterpret_cast<const float4*>(wp + ks * 32 + 4));
  }

  const int mtiles = (N + 15) >> 4;
  for (int mt = blockIdx.x; mt < mtiles; mt += gridDim.x) {
    const int arow = min(mt * 16 + l15, N - 1);
    const float* ap = A + (size_t)arow * D + quad * 8;
    B8 a[4];
#pragma unroll
    for (int ks = 0; ks < 4; ++ks)
      a[ks] = pack8(*reinterpret_cast<const float4*>(ap + ks * 32),
                    *reinterpret_cast<const float4*>(ap + ks * 32 + 4));
#pragma unroll
    for (int t = 0; t < 2; ++t) {
      f32x4 acc = {0.f, 0.f, 0.f, 0.f};
#pragma unroll
      for (int ks = 0; ks < 4; ++ks)
        acc = __builtin_amdgcn_mfma_f32_16x16x32_bf16(a[ks].v, bfrag[t][ks].v, acc, 0, 0, 0);
      const int col = wave * 32 + t * 16 + l15;
#pragma unroll
      for (int r = 0; r < 4; ++r) {
        const int orow = mt * 16 + quad * 4 + r;
        if (orow < N) {
          union { __bf16 b; ushort s; } c;
          c.b = (__bf16)acc[r];
          Z[(size_t)orow * D + col] = c.s;
        }
      }
    }
  }
}

// ---- z2 = h1(bf16) @ W2^T, bf16 out (no bias/relu) -----------------------

__global__ __launch_bounds__(256) void k_gemmz2(const ushort* __restrict__ A,
                                                const float* __restrict__ W,
                                                ushort* __restrict__ Z, int N) {
  const int wave = threadIdx.x >> 6;
  const int lane = threadIdx.x & 63;
  const int l15 = lane & 15;
  const int quad = lane >> 4;

  B8 bfrag[2][4];
#pragma unroll
  for (int t = 0; t < 2; ++t) {
    const int n = wave * 32 + t * 16 + l15;
    const float* wp = W + (size_t)n * D + quad * 8;
#pragma unroll
    for (int ks = 0; ks < 4; ++ks)
      bfrag[t][ks] = pack8(*reinterpret_cast<const float4*>(wp + ks * 32),
                           *reinterpret_cast<const float4*>(wp + ks * 32 + 4));
  }

  const int mtiles = (N + 15) >> 4;
  for (int mt = blockIdx.x; mt < mtiles; mt += gridDim.x) {
    const int arow = min(mt * 16 + l15, N - 1);
    const ushort* ap = A + (size_t)arow * D + quad * 8;
    B8 a[4];
#pragma unroll
    for (int ks = 0; ks < 4; ++ks)
      a[ks].u = *reinterpret_cast<const uint4*>(ap + ks * 32);
#pragma unroll
    for (int t = 0; t < 2; ++t) {
      f32x4 acc = {0.f, 0.f, 0.f, 0.f};
#pragma unroll
      for (int ks = 0; ks < 4; ++ks)
        acc = __builtin_amdgcn_mfma_f32_16x16x32_bf16(a[ks].v, bfrag[t][ks].v, acc, 0, 0, 0);
      const int col = wave * 32 + t * 16 + l15;
#pragma unroll
      for (int r = 0; r < 4; ++r) {
        const int orow = mt * 16 + quad * 4 + r;
        if (orow < N) {
          union { __bf16 b; ushort s; } c;
          c.b = (__bf16)acc[r];
          Z[(size_t)orow * D + col] = c.s;
        }
      }
    }
  }
}

// ---- gather core: packed f32 accumulate of 8 bf16 ------------------------
// 16-lane group per node; lane w owns feature slot [w*8, w*8+8).
// 4 rows in flight (round-2 proven config: VGPR 28, ~70% occupancy).

__device__ __forceinline__ void accp(f32x2& a, unsigned int u) {
  f32x2 v;
  v.x = __uint_as_float(u << 16);
  v.y = __uint_as_float(u & 0xffff0000u);
  a += v;
}

__device__ __forceinline__ void acc8p(f32x2 acc[4], const uint4& u) {
  accp(acc[0], u.x);
  accp(acc[1], u.y);
  accp(acc[2], u.z);
  accp(acc[3], u.w);
}

__device__ __forceinline__ void gather_acc(const ushort* __restrict__ hp,
                                           const int* __restrict__ esrc,
                                           int beg, int end, f32x2 acc[4]) {
  int e = beg;
  for (; e + 3 < end; e += 4) {
    const int4 ss = *reinterpret_cast<const int4*>(esrc + e);
    const uint4 u0 = *reinterpret_cast<const uint4*>(hp + (size_t)ss.x * D);
    const uint4 u1 = *reinterpret_cast<const uint4*>(hp + (size_t)ss.y * D);
    const uint4 u2 = *reinterpret_cast<const uint4*>(hp + (size_t)ss.z * D);
    const uint4 u3 = *reinterpret_cast<const uint4*>(hp + (size_t)ss.w * D);
    acc8p(acc, u0);
    acc8p(acc, u1);
    acc8p(acc, u2);
    acc8p(acc, u3);
  }
  for (; e < end; ++e) {
    const int s0 = esrc[e];
    const uint4 u0 = *reinterpret_cast<const uint4*>(hp + (size_t)s0 * D);
    acc8p(acc, u0);
  }
}

// ---- layer 1: h1 = relu(mean_gather(z1) + b1) ----------------------------

__global__ __launch_bounds__(256) void k_gather_relu(const ushort* __restrict__ z,
                                                     const int* __restrict__ row_ptr,
                                                     const int* __restrict__ esrc,
                                                     const float* __restrict__ inv,
                                                     const float* __restrict__ bias,
                                                     ushort* __restrict__ out, int N) {
  const int g = threadIdx.x >> 4;   // node within tile
  const int w = threadIdx.x & 15;   // feature slot
  const ushort* hp = z + w * 8;
  float bb[8];
  {
    const float4 x = *reinterpret_cast<const float4*>(bias + w * 8);
    const float4 y = *reinterpret_cast<const float4*>(bias + w * 8 + 4);
    bb[0] = x.x; bb[1] = x.y; bb[2] = x.z; bb[3] = x.w;
    bb[4] = y.x; bb[5] = y.y; bb[6] = y.z; bb[7] = y.w;
  }
  const int ntiles = (N + 15) >> 4;
  for (int tile = blockIdx.x; tile < ntiles; tile += gridDim.x) {
    const int node = tile * 16 + g;
    if (node >= N) continue;
    f32x2 acc[4] = {{0.f, 0.f}, {0.f, 0.f}, {0.f, 0.f}, {0.f, 0.f}};
    gather_acc(hp, esrc, row_ptr[node], row_ptr[node + 1], acc);
    const float iv = inv[node];
    union { __bf16 b[8]; uint4 u; } p;
#pragma unroll
    for (int i = 0; i < 4; ++i) {
      p.b[i * 2 + 0] = (__bf16)fmaxf(acc[i].x * iv + bb[i * 2 + 0], 0.f);
      p.b[i * 2 + 1] = (__bf16)fmaxf(acc[i].y * iv + bb[i * 2 + 1], 0.f);
    }
    *reinterpret_cast<uint4*>(out + (size_t)node * D + w * 8) = p.u;
  }
}

// ---- layer 2: gather z2 -> h2(LDS) -> logits MFMA -> log_softmax ---------

__global__ __launch_bounds__(256, 4) void k_gather_logits(const ushort* __restrict__ z2,
                                                          const ushort* __restrict__ h1,
                                                          const int* __restrict__ row_ptr,
                                                          const int* __restrict__ esrc,
                                                          const float* __restrict__ inv,
                                                          const float* __restrict__ b2,
                                                          const float* __restrict__ Wl,
                                                          const float* __restrict__ bl,
                                                          float* __restrict__ out, int N) {
  __shared__ ushort H2t[16][136];
  __shared__ float L[16][NCLS + 4];
  const int wave = threadIdx.x >> 6;
  const int lane = threadIdx.x & 63;
  const int l15 = lane & 15;
  const int quad = lane >> 4;
  const int g = threadIdx.x >> 4;
  const int w = threadIdx.x & 15;
  const ushort* hp = z2 + w * 8;

  float bb[8];
  {
    const float4 x = *reinterpret_cast<const float4*>(b2 + w * 8);
    const float4 y = *reinterpret_cast<const float4*>(b2 + w * 8 + 4);
    bb[0] = x.x; bb[1] = x.y; bb[2] = x.z; bb[3] = x.w;
    bb[4] = y.x; bb[5] = y.y; bb[6] = y.z; bb[7] = y.w;
  }
  B8 bfragL[8];
  const int nlc = wave * 16 + l15;
  const float bbl = bl[nlc];
  {
    const float* wp = Wl + (size_t)nlc * (2 * D) + quad * 8;
#pragma unroll
    for (int ks = 0; ks < 8; ++ks)
      bfragL[ks] = pack8(*reinterpret_cast<const float4*>(wp + ks * 32),
                         *reinterpret_cast<const float4*>(wp + ks * 32 + 4));
  }

  const int mtiles = (N + 15) >> 4;
  for (int mt = blockIdx.x; mt < mtiles; mt += gridDim.x) {
    // ---- gather z2, epilogue h2 = relu(mean + b2) -> LDS ----
    const int node = mt * 16 + g;
    f32x2 acc[4] = {{0.f, 0.f}, {0.f, 0.f}, {0.f, 0.f}, {0.f, 0.f}};
    float iv = 0.f;
    if (node < N) {
      gather_acc(hp, esrc, row_ptr[node], row_ptr[node + 1], acc);
      iv = inv[node];
    }
    union { __bf16 b[8]; uint4 u; } p;
#pragma unroll
    for (int i = 0; i < 4; ++i) {
      p.b[i * 2 + 0] = (__bf16)fmaxf(acc[i].x * iv + bb[i * 2 + 0], 0.f);
      p.b[i * 2 + 1] = (__bf16)fmaxf(acc[i].y * iv + bb[i * 2 + 1], 0.f);
    }
    *reinterpret_cast<uint4*>(&H2t[g][w * 8]) = p.u;
    __syncthreads();
    // ---- logits = [h1 | h2] @ Wl^T + bl ----
    {
      const int arow = min(mt * 16 + l15, N - 1);
      const ushort* h1p = h1 + (size_t)arow * D + quad * 8;
      f32x4 acL = {0.f, 0.f, 0.f, 0.f};
      B8 a;
#pragma unroll
      for (int ks = 0; ks < 4; ++ks) {
        a.u = *reinterpret_cast<const uint4*>(h1p + ks * 32);
        acL = __builtin_amdgcn_mfma_f32_16x16x32_bf16(a.v, bfragL[ks].v, acL, 0, 0, 0);
      }
#pragma unroll
      for (int ks = 0; ks < 4; ++ks) {
        a.u = *reinterpret_cast<const uint4*>(&H2t[l15][ks * 32 + quad * 8]);
        acL = __builtin_amdgcn_mfma_f32_16x16x32_bf16(a.v, bfragL[4 + ks].v, acL, 0, 0, 0);
      }
#pragma unroll
      for (int r = 0; r < 4; ++r)
        L[quad * 4 + r][wave * 16 + l15] = acL[r] + bbl;
    }
    __syncthreads();
    // ---- log_softmax ----
#pragma unroll
    for (int r = 0; r < 4; ++r) {
      const int row = wave * 4 + r;
      float v = L[row][lane];
      float m = v;
#pragma unroll
      for (int off = 32; off > 0; off >>= 1) m = fmaxf(m, __shfl_xor(m, off));
      float e = __expf(v - m);
#pragma unroll
      for (int off = 32; off > 0; off >>= 1) e += __shfl_xor(e, off);
      const int orow = mt * 16 + row;
      if (orow < N) out[(size_t)orow * NCLS + lane] = v - m - __logf(e);
    }
    __syncthreads();
  }
}

// ---- driver --------------------------------------------------------------

extern "C" void kernel_launch(void* const* d_in, const int* in_sizes, int n_in,
                              void* d_out, int out_size, void* d_ws, size_t ws_size,
                              hipStream_t stream) {
  const float* feat = (const float*)d_in[0];
  const int* src = (const int*)d_in[1];
  const int* dst = (const int*)d_in[2];
  const float* W1 = (const float*)d_in[3];
  const float* b1 = (const float*)d_in[4];
  const float* W2 = (const float*)d_in[5];
  const float* b2 = (const float*)d_in[6];
  const float* Wl = (const float*)d_in[7];
  const float* bl = (const float*)d_in[8];
  float* out = (float*)d_out;

  const int N = in_sizes[0] / D;  // 100000
  const int E = in_sizes[1];      // 1600000
  const int NB = (N + 127) >> BSH;  // 782

  // workspace layout
  float* ws = (float*)d_ws;
  float* inv = ws;                          // N
  ushort* z1 = (ushort*)(inv + N);          // N*D  (feat @ W1^T)
  ushort* h1b = z1 + (size_t)N * D;         // N*D
  ushort* z2 = h1b + (size_t)N * D;         // N*D  (ebuck aliases; dead after bbuild)
  int* row_ptr = (int*)(z2 + (size_t)N * D);  // N+1
  int* esrc = row_ptr + N + 1;              // E
  int* bcnt = esrc + E;                     // NBMAX
  int* bbase = bcnt + NBMAX;                // NBMAX+1
  int* bcur = bbase + NBMAX + 1;            // NBMAX
  int* ebuck = (int*)z2;                    // E ints, overwritten later by z2

  // bucketed CSR build
  hipMemsetAsync(bcnt, 0, NBMAX * sizeof(int), stream);
  k_bhist<<<256, 256, 0, stream>>>(dst, bcnt, E, NB);
  k_bscan<<<1, 1024, 0, stream>>>(bcnt, bbase, bcur, NB, E);
  k_bscatter<<<(E + CCHUNK - 1) / CCHUNK, 256, 0, stream>>>(src, dst, bcur, ebuck, E, NB);
  k_bbuild<<<NB, 256, 0, stream>>>(ebuck, bbase, row_ptr, esrc, inv, N, E);

  // layer 1: project first (mean is linear), then gather with relu epilogue
  k_gemmz1<<<2048, 256, 0, stream>>>(feat, W1, z1, N);
  k_gather_relu<<<2048, 256, 0, stream>>>(z1, row_ptr, esrc, inv, b1, h1b, N);

  // layer 2: project h1, then gather + logits + log_softmax fused
  k_gemmz2<<<2048, 256, 0, stream>>>(h1b, W2, z2, N);
  k_gather_logits<<<2048, 256, 0, stream>>>(z2, h1b, row_ptr, esrc, inv, b2, Wl, bl, out, N);
}

// Round 6
// 389.821 us; speedup vs baseline: 1.0294x; 1.0294x over previous
//
#include <hip/hip_runtime.h>
#include <hip/hip_fp8.h>
#include <stdint.h>

#define D 128
#define NCLS 64
#define BSH 7       // 128 nodes per bucket
#define NBMAX 1024  // max buckets (N <= 131072)
#define CCHUNK 4096 // edges per k_bscatter block

typedef __bf16 bf16x8 __attribute__((ext_vector_type(8)));
typedef float f32x4 __attribute__((ext_vector_type(4)));
typedef float f32x2 __attribute__((ext_vector_type(2)));

union B8 { uint4 u; bf16x8 v; };

// pack 8 f32 -> 8 bf16 fragment
__device__ __forceinline__ B8 pack8(const float4& a, const float4& b) {
  union { __bf16 h[8]; uint4 u; } p;
  p.h[0] = (__bf16)a.x; p.h[1] = (__bf16)a.y; p.h[2] = (__bf16)a.z; p.h[3] = (__bf16)a.w;
  p.h[4] = (__bf16)b.x; p.h[5] = (__bf16)b.y; p.h[6] = (__bf16)b.z; p.h[7] = (__bf16)b.w;
  B8 r; r.u = p.u; return r;
}

// ---- bucketed CSR build (proven R0-R4) -----------------------------------

__global__ __launch_bounds__(256) void k_bhist(const int* __restrict__ dst,
                                               int* __restrict__ bcnt, int E, int NB) {
  __shared__ int h[NBMAX];
  for (int i = threadIdx.x; i < NB; i += 256) h[i] = 0;
  __syncthreads();
  for (int e = blockIdx.x * 256 + threadIdx.x; e < E; e += gridDim.x * 256)
    atomicAdd(&h[dst[e] >> BSH], 1);
  __syncthreads();
  for (int i = threadIdx.x; i < NB; i += 256) {
    int c = h[i];
    if (c) atomicAdd(&bcnt[i], c);
  }
}

__global__ __launch_bounds__(1024) void k_bscan(const int* __restrict__ bcnt,
                                                int* __restrict__ bbase,
                                                int* __restrict__ bcur, int NB, int E) {
  __shared__ int sm[NBMAX];
  const int tid = threadIdx.x;
  int v = (tid < NB) ? bcnt[tid] : 0;
  sm[tid] = v;
  __syncthreads();
  for (int off = 1; off < NBMAX; off <<= 1) {
    int t = (tid >= off) ? sm[tid - off] : 0;
    __syncthreads();
    sm[tid] += t;
    __syncthreads();
  }
  if (tid < NB) {
    bbase[tid] = sm[tid] - v;
    bcur[tid] = sm[tid] - v;
  }
  if (tid == 0) bbase[NB] = E;
}

__global__ __launch_bounds__(256) void k_bscatter(const int* __restrict__ src,
                                                  const int* __restrict__ dst,
                                                  int* __restrict__ bcur,
                                                  int* __restrict__ ebuck, int E, int NB) {
  __shared__ int h[NBMAX];
  __shared__ int base[NBMAX];
  const int beg = blockIdx.x * CCHUNK;
  const int end = min(beg + CCHUNK, E);
  for (int i = threadIdx.x; i < NB; i += 256) h[i] = 0;
  __syncthreads();
  for (int e = beg + threadIdx.x; e < end; e += 256)
    atomicAdd(&h[dst[e] >> BSH], 1);
  __syncthreads();
  for (int i = threadIdx.x; i < NB; i += 256) {
    int c = h[i];
    base[i] = c ? atomicAdd(&bcur[i], c) : 0;
    h[i] = 0;  // becomes local rank cursor
  }
  __syncthreads();
  for (int e = beg + threadIdx.x; e < end; e += 256) {
    const int d = dst[e];
    const int b = d >> BSH;
    const int r = atomicAdd(&h[b], 1);
    ebuck[base[b] + r] = (src[e] << BSH) | (d & 127);
  }
}

__global__ __launch_bounds__(256) void k_bbuild(const int* __restrict__ ebuck,
                                                const int* __restrict__ bbase,
                                                int* __restrict__ row_ptr,
                                                int* __restrict__ esrc,
                                                float* __restrict__ inv, int N, int E) {
  __shared__ int cnt[128], s[128], cur[128];
  const int b = blockIdx.x;
  const int n0 = b << BSH;
  const int nn = min(128, N - n0);
  const int beg = bbase[b], end = bbase[b + 1];
  const int tid = threadIdx.x;
  if (tid < 128) cnt[tid] = 0;
  __syncthreads();
  for (int e = beg + tid; e < end; e += 256)
    atomicAdd(&cnt[ebuck[e] & 127], 1);
  __syncthreads();
  if (tid < 128) s[tid] = cnt[tid];
  __syncthreads();
  for (int off = 1; off < 128; off <<= 1) {
    int t = (tid < 128 && tid >= off) ? s[tid - off] : 0;
    __syncthreads();
    if (tid < 128) s[tid] += t;
    __syncthreads();
  }
  if (tid < 128) {
    const int ex = s[tid] - cnt[tid];
    cur[tid] = ex;
    if (tid < nn) {
      row_ptr[n0 + tid] = beg + ex;
      inv[n0 + tid] = 1.0f / fmaxf((float)cnt[tid], 1.0f);
    }
  }
  if (b == 0 && tid == 0) row_ptr[N] = E;
  __syncthreads();
  for (int e = beg + tid; e < end; e += 256) {
    const int p = ebuck[e];
    const int r = atomicAdd(&cur[p & 127], 1);
    esrc[beg + r] = p >> BSH;
  }
}

// ---- z1 = feat(f32) @ W1^T, fp8 e4m3 out ---------------------------------

__global__ __launch_bounds__(256) void k_gemmz1(const float* __restrict__ A,
                                                const float* __restrict__ W,
                                                unsigned char* __restrict__ Z, int N) {
  const int wave = threadIdx.x >> 6;
  const int lane = threadIdx.x & 63;
  const int l15 = lane & 15;
  const int quad = lane >> 4;

  B8 bfrag[2][4];
#pragma unroll
  for (int t = 0; t < 2; ++t) {
    const int n = wave * 32 + t * 16 + l15;
    const float* wp = W + (size_t)n * D + quad * 8;
#pragma unroll
    for (int ks = 0; ks < 4; ++ks)
      bfrag[t][ks] = pack8(*reinterpret_cast<const float4*>(wp + ks * 32),
                           *reinterpret_cast<const float4*>(wp + ks * 32 + 4));
  }

  const int mtiles = (N + 15) >> 4;
  for (int mt = blockIdx.x; mt < mtiles; mt += gridDim.x) {
    const int arow = min(mt * 16 + l15, N - 1);
    const float* ap = A + (size_t)arow * D + quad * 8;
    B8 a[4];
#pragma unroll
    for (int ks = 0; ks < 4; ++ks)
      a[ks] = pack8(*reinterpret_cast<const float4*>(ap + ks * 32),
                    *reinterpret_cast<const float4*>(ap + ks * 32 + 4));
#pragma unroll
    for (int t = 0; t < 2; ++t) {
      f32x4 acc = {0.f, 0.f, 0.f, 0.f};
#pragma unroll
      for (int ks = 0; ks < 4; ++ks)
        acc = __builtin_amdgcn_mfma_f32_16x16x32_bf16(a[ks].v, bfrag[t][ks].v, acc, 0, 0, 0);
      const int col = wave * 32 + t * 16 + l15;
#pragma unroll
      for (int r = 0; r < 4; ++r) {
        const int orow = mt * 16 + quad * 4 + r;
        if (orow < N) {
          __hip_fp8_e4m3 q((float)acc[r]);
          Z[(size_t)orow * D + col] = q.__x;
        }
      }
    }
  }
}

// ---- z2 = h1(bf16) @ W2^T, fp8 e4m3 out ----------------------------------

__global__ __launch_bounds__(256) void k_gemmz2(const ushort* __restrict__ A,
                                                const float* __restrict__ W,
                                                unsigned char* __restrict__ Z, int N) {
  const int wave = threadIdx.x >> 6;
  const int lane = threadIdx.x & 63;
  const int l15 = lane & 15;
  const int quad = lane >> 4;

  B8 bfrag[2][4];
#pragma unroll
  for (int t = 0; t < 2; ++t) {
    const int n = wave * 32 + t * 16 + l15;
    const float* wp = W + (size_t)n * D + quad * 8;
#pragma unroll
    for (int ks = 0; ks < 4; ++ks)
      bfrag[t][ks] = pack8(*reinterpret_cast<const float4*>(wp + ks * 32),
                           *reinterpret_cast<const float4*>(wp + ks * 32 + 4));
  }

  const int mtiles = (N + 15) >> 4;
  for (int mt = blockIdx.x; mt < mtiles; mt += gridDim.x) {
    const int arow = min(mt * 16 + l15, N - 1);
    const ushort* ap = A + (size_t)arow * D + quad * 8;
    B8 a[4];
#pragma unroll
    for (int ks = 0; ks < 4; ++ks)
      a[ks].u = *reinterpret_cast<const uint4*>(ap + ks * 32);
#pragma unroll
    for (int t = 0; t < 2; ++t) {
      f32x4 acc = {0.f, 0.f, 0.f, 0.f};
#pragma unroll
      for (int ks = 0; ks < 4; ++ks)
        acc = __builtin_amdgcn_mfma_f32_16x16x32_bf16(a[ks].v, bfrag[t][ks].v, acc, 0, 0, 0);
      const int col = wave * 32 + t * 16 + l15;
#pragma unroll
      for (int r = 0; r < 4; ++r) {
        const int orow = mt * 16 + quad * 4 + r;
        if (orow < N) {
          __hip_fp8_e4m3 q((float)acc[r]);
          Z[(size_t)orow * D + col] = q.__x;
        }
      }
    }
  }
}

// ---- gather core: fp8 rows, f32 accumulate -------------------------------
// 16-lane group per node; lane w owns feature slot [w*8, w*8+8).
// fp8 rows are 128B: lane loads uint2 (8 fp8). 4 rows in flight.

__device__ __forceinline__ void accq8(f32x2 acc[4], const uint2& u) {
  union { uint2 v; unsigned char b[8]; } t;
  t.v = u;
#pragma unroll
  for (int i = 0; i < 4; ++i) {
    __hip_fp8_e4m3 f0, f1;
    f0.__x = t.b[2 * i];
    f1.__x = t.b[2 * i + 1];
    f32x2 d;
    d.x = (float)f0;
    d.y = (float)f1;
    acc[i] += d;
  }
}

__device__ __forceinline__ void gather_acc8(const unsigned char* __restrict__ hp,
                                            const int* __restrict__ esrc,
                                            int beg, int end, f32x2 acc[4]) {
  int e = beg;
  for (; e + 3 < end; e += 4) {
    const int4 ss = *reinterpret_cast<const int4*>(esrc + e);
    const uint2 u0 = *reinterpret_cast<const uint2*>(hp + (size_t)ss.x * D);
    const uint2 u1 = *reinterpret_cast<const uint2*>(hp + (size_t)ss.y * D);
    const uint2 u2 = *reinterpret_cast<const uint2*>(hp + (size_t)ss.z * D);
    const uint2 u3 = *reinterpret_cast<const uint2*>(hp + (size_t)ss.w * D);
    accq8(acc, u0);
    accq8(acc, u1);
    accq8(acc, u2);
    accq8(acc, u3);
  }
  for (; e < end; ++e) {
    const int s0 = esrc[e];
    const uint2 u0 = *reinterpret_cast<const uint2*>(hp + (size_t)s0 * D);
    accq8(acc, u0);
  }
}

// ---- h = relu(mean_gather(z_fp8) + bias) -- barrier-free pure gather -----

__global__ __launch_bounds__(256) void k_gather_relu(const unsigned char* __restrict__ z,
                                                     const int* __restrict__ row_ptr,
                                                     const int* __restrict__ esrc,
                                                     const float* __restrict__ inv,
                                                     const float* __restrict__ bias,
                                                     ushort* __restrict__ out, int N) {
  const int g = threadIdx.x >> 4;   // node within tile
  const int w = threadIdx.x & 15;   // feature slot
  const unsigned char* hp = z + w * 8;
  float bb[8];
  {
    const float4 x = *reinterpret_cast<const float4*>(bias + w * 8);
    const float4 y = *reinterpret_cast<const float4*>(bias + w * 8 + 4);
    bb[0] = x.x; bb[1] = x.y; bb[2] = x.z; bb[3] = x.w;
    bb[4] = y.x; bb[5] = y.y; bb[6] = y.z; bb[7] = y.w;
  }
  const int ntiles = (N + 15) >> 4;
  for (int tile = blockIdx.x; tile < ntiles; tile += gridDim.x) {
    const int node = tile * 16 + g;
    if (node >= N) continue;
    f32x2 acc[4] = {{0.f, 0.f}, {0.f, 0.f}, {0.f, 0.f}, {0.f, 0.f}};
    gather_acc8(hp, esrc, row_ptr[node], row_ptr[node + 1], acc);
    const float iv = inv[node];
    union { __bf16 b[8]; uint4 u; } p;
#pragma unroll
    for (int i = 0; i < 4; ++i) {
      p.b[i * 2 + 0] = (__bf16)fmaxf(acc[i].x * iv + bb[i * 2 + 0], 0.f);
      p.b[i * 2 + 1] = (__bf16)fmaxf(acc[i].y * iv + bb[i * 2 + 1], 0.f);
    }
    *reinterpret_cast<uint4*>(out + (size_t)node * D + w * 8) = p.u;
  }
}

// ---- logits = [h1 | h2] @ Wl^T + bl -> log_softmax (streaming) -----------

__global__ __launch_bounds__(256) void k_logits(const ushort* __restrict__ h1,
                                                const ushort* __restrict__ h2,
                                                const float* __restrict__ Wl,
                                                const float* __restrict__ bl,
                                                float* __restrict__ out, int N) {
  __shared__ float L[16][NCLS + 4];
  const int wave = threadIdx.x >> 6;
  const int lane = threadIdx.x & 63;
  const int l15 = lane & 15;
  const int quad = lane >> 4;

  B8 bfragL[8];
  const int nlc = wave * 16 + l15;
  const float bbl = bl[nlc];
  {
    const float* wp = Wl + (size_t)nlc * (2 * D) + quad * 8;
#pragma unroll
    for (int ks = 0; ks < 8; ++ks)
      bfragL[ks] = pack8(*reinterpret_cast<const float4*>(wp + ks * 32),
                         *reinterpret_cast<const float4*>(wp + ks * 32 + 4));
  }

  const int mtiles = (N + 15) >> 4;
  for (int mt = blockIdx.x; mt < mtiles; mt += gridDim.x) {
    const int arow = min(mt * 16 + l15, N - 1);
    const ushort* p1 = h1 + (size_t)arow * D + quad * 8;
    const ushort* p2 = h2 + (size_t)arow * D + quad * 8;
    f32x4 acc = {0.f, 0.f, 0.f, 0.f};
    B8 a;
#pragma unroll
    for (int ks = 0; ks < 4; ++ks) {
      a.u = *reinterpret_cast<const uint4*>(p1 + ks * 32);
      acc = __builtin_amdgcn_mfma_f32_16x16x32_bf16(a.v, bfragL[ks].v, acc, 0, 0, 0);
    }
#pragma unroll
    for (int ks = 0; ks < 4; ++ks) {
      a.u = *reinterpret_cast<const uint4*>(p2 + ks * 32);
      acc = __builtin_amdgcn_mfma_f32_16x16x32_bf16(a.v, bfragL[4 + ks].v, acc, 0, 0, 0);
    }
#pragma unroll
    for (int r = 0; r < 4; ++r)
      L[quad * 4 + r][wave * 16 + l15] = acc[r] + bbl;
    __syncthreads();
#pragma unroll
    for (int r = 0; r < 4; ++r) {
      const int row = wave * 4 + r;
      float v = L[row][lane];
      float m = v;
#pragma unroll
      for (int off = 32; off > 0; off >>= 1) m = fmaxf(m, __shfl_xor(m, off));
      float e = __expf(v - m);
#pragma unroll
      for (int off = 32; off > 0; off >>= 1) e += __shfl_xor(e, off);
      const int orow = mt * 16 + row;
      if (orow < N) out[(size_t)orow * NCLS + lane] = v - m - __logf(e);
    }
    __syncthreads();
  }
}

// ---- driver --------------------------------------------------------------

extern "C" void kernel_launch(void* const* d_in, const int* in_sizes, int n_in,
                              void* d_out, int out_size, void* d_ws, size_t ws_size,
                              hipStream_t stream) {
  const float* feat = (const float*)d_in[0];
  const int* src = (const int*)d_in[1];
  const int* dst = (const int*)d_in[2];
  const float* W1 = (const float*)d_in[3];
  const float* b1 = (const float*)d_in[4];
  const float* W2 = (const float*)d_in[5];
  const float* b2 = (const float*)d_in[6];
  const float* Wl = (const float*)d_in[7];
  const float* bl = (const float*)d_in[8];
  float* out = (float*)d_out;

  const int N = in_sizes[0] / D;  // 100000
  const int E = in_sizes[1];      // 1600000
  const int NB = (N + 127) >> BSH;  // 782

  // workspace layout
  float* ws = (float*)d_ws;
  float* inv = ws;                               // N f32
  ushort* h1b = (ushort*)(inv + N);              // N*D bf16
  ushort* h2b = h1b + (size_t)N * D;             // N*D bf16
  unsigned char* z8 = (unsigned char*)(h2b + (size_t)N * D);  // N*D fp8 (ebuck aliases)
  int* row_ptr = (int*)(z8 + (size_t)N * D);     // N+1
  int* esrc = row_ptr + N + 1;                   // E
  int* bcnt = esrc + E;                          // NBMAX
  int* bbase = bcnt + NBMAX;                     // NBMAX+1
  int* bcur = bbase + NBMAX + 1;                 // NBMAX
  int* ebuck = (int*)z8;                         // E ints, dead after k_bbuild

  hipMemsetAsync(bcnt, 0, NBMAX * sizeof(int), stream);

  // bucketed CSR build (split, proven)
  k_bhist<<<256, 256, 0, stream>>>(dst, bcnt, E, NB);
  k_bscan<<<1, 1024, 0, stream>>>(bcnt, bbase, bcur, NB, E);
  k_bscatter<<<(E + CCHUNK - 1) / CCHUNK, 256, 0, stream>>>(src, dst, bcur, ebuck, E, NB);
  k_bbuild<<<NB, 256, 0, stream>>>(ebuck, bbase, row_ptr, esrc, inv, N, E);

  // layer 1: project first (mean is linear), fp8 z-table, pure gather
  k_gemmz1<<<2048, 256, 0, stream>>>(feat, W1, z8, N);
  k_gather_relu<<<2048, 256, 0, stream>>>(z8, row_ptr, esrc, inv, b1, h1b, N);

  // layer 2: project h1, fp8 z-table, pure gather, streaming logits
  k_gemmz2<<<2048, 256, 0, stream>>>(h1b, W2, z8, N);
  k_gather_relu<<<2048, 256, 0, stream>>>(z8, row_ptr, esrc, inv, b2, h2b, N);
  k_logits<<<2048, 256, 0, stream>>>(h1b, h2b, Wl, bl, out, N);
}